// Round 11
// baseline (35.234 us; speedup 1.0000x reference)
//
#include <hip/hip_runtime.h>
#include <math.h>

#define C   256
#define FC  256
#define H   32
#define W   32
#define HW  1024
#define KH  7
#define KW  7
#define PAD 3
#define KK  49

typedef short s16x4 __attribute__((ext_vector_type(4)));
typedef short s16x8 __attribute__((ext_vector_type(8)));
typedef float f32x4 __attribute__((ext_vector_type(4)));

__device__ __forceinline__ ushort f2bf(float f) {
    uint u = __float_as_uint(f);
    u += 0x7FFFu + ((u >> 16) & 1u);       // round-to-nearest-even
    return (ushort)(u >> 16);
}
__device__ __forceinline__ float bf2f(ushort u) {
    return __uint_as_float(((uint)u) << 16);
}
__device__ __forceinline__ s16x8 pack8(const float* v) {
    s16x8 r;
    #pragma unroll
    for (int j = 0; j < 8; ++j) r[j] = (short)f2bf(v[j]);
    return r;
}

// ---------------------------------------------------------------------------
// Kernel 1: fused q/k/v projection, direct from x/W (unchanged — control).
// Output layout (b, px, f), f-contiguous.
// ---------------------------------------------------------------------------
__global__ __launch_bounds__(256) void qkv_direct_kernel(
    const float* __restrict__ x,  const float* __restrict__ Wq,
    const float* __restrict__ Wk, const float* __restrict__ Wv,
    ushort* __restrict__ qo, ushort* __restrict__ ko, ushort* __restrict__ vo)
{
    const int t   = threadIdx.x;
    const int pxt = blockIdx.x;        // 0..15
    const int fg  = blockIdx.y;        // 0..7
    const int b   = blockIdx.z;        // 0..3

    const int wid = t >> 6, lane = t & 63;
    const int wf = wid >> 1, wp = wid & 1;
    const int lr = lane & 15;
    const int g  = lane >> 4;
    const int fbase = fg * 32 + wf * 16;
    const int px0   = pxt * 64 + wp * 32 + lr;

    const float* wqp = Wq + (size_t)(g * 8) * FC + fbase + lr;
    const float* wkp = Wk + (size_t)(g * 8) * FC + fbase + lr;
    const float* wvp = Wv + (size_t)(g * 8) * FC + fbase + lr;
    const float* xp0 = x + ((size_t)b * C + g * 8) * HW + px0;
    const float* xp1 = xp0 + 16;

    f32x4 accq0 = {0.f,0.f,0.f,0.f}, accq1 = {0.f,0.f,0.f,0.f};
    f32x4 acck0 = {0.f,0.f,0.f,0.f}, acck1 = {0.f,0.f,0.f,0.f};
    f32x4 accv0 = {0.f,0.f,0.f,0.f}, accv1 = {0.f,0.f,0.f,0.f};

    #pragma unroll
    for (int kk = 0; kk < 8; ++kk) {
        const int co = kk * 32;
        float aq[8], ak[8], av[8], b0[8], b1[8];
        #pragma unroll
        for (int j = 0; j < 8; ++j) {
            aq[j] = wqp[(size_t)(co + j) * FC];
            ak[j] = wkp[(size_t)(co + j) * FC];
            av[j] = wvp[(size_t)(co + j) * FC];
            b0[j] = xp0[(size_t)(co + j) * HW];
            b1[j] = xp1[(size_t)(co + j) * HW];
        }
        s16x8 X0 = pack8(b0), X1 = pack8(b1);
        s16x8 WQ = pack8(aq), WK = pack8(ak), WV = pack8(av);
        accq0 = __builtin_amdgcn_mfma_f32_16x16x32_bf16(X0, WQ, accq0, 0, 0, 0);
        accq1 = __builtin_amdgcn_mfma_f32_16x16x32_bf16(X1, WQ, accq1, 0, 0, 0);
        acck0 = __builtin_amdgcn_mfma_f32_16x16x32_bf16(X0, WK, acck0, 0, 0, 0);
        acck1 = __builtin_amdgcn_mfma_f32_16x16x32_bf16(X1, WK, acck1, 0, 0, 0);
        accv0 = __builtin_amdgcn_mfma_f32_16x16x32_bf16(X0, WV, accv0, 0, 0, 0);
        accv1 = __builtin_amdgcn_mfma_f32_16x16x32_bf16(X1, WV, accv1, 0, 0, 0);
    }

    #pragma unroll
    for (int j = 0; j < 4; ++j) {
        int pxr = pxt * 64 + wp * 32 + g * 4 + j;
        size_t a0 = ((size_t)(b * HW) + pxr) * FC + fbase + lr;
        size_t a1 = a0 + (size_t)16 * FC;
        qo[a0] = f2bf(accq0[j]);  qo[a1] = f2bf(accq1[j]);
        ko[a0] = f2bf(acck0[j]);  ko[a1] = f2bf(acck1[j]);
        vo[a0] = f2bf(accv0[j]);  vo[a1] = f2bf(accv1[j]);
    }
}

// ---------------------------------------------------------------------------
// Kernel 2: windowed softmax attention, v5 (R10 fix: __builtin_amdgcn_exp2f).
// Block = 16x16 px tile x 4 channels; grid (4,64,4) = 1024 blocks = 4/CU.
//  - dy-outer, fully unrolled 7x7 with row-batched LDS loads (static idx).
//  - rel via block-uniform global loads (s_load path), no rel in LDS.
//  - exp(q*(k+rel)) = exp2(q2*(k+rel)) with q2 = q*log2(e), v_exp_f32.
// Single-pass softmax without max-sub (|s| << 88 in f32 — safe).
// ---------------------------------------------------------------------------
__global__ __launch_bounds__(256) void attn_kernel(
    const ushort* __restrict__ q, const ushort* __restrict__ k,
    const ushort* __restrict__ v,
    const float* __restrict__ rel_x, const float* __restrict__ rel_y,
    const float* __restrict__ bias, float* __restrict__ out)
{
    __shared__ f32x4 ksf[484];
    __shared__ f32x4 vsf[484];

    const int b    = blockIdx.z;
    const int fg   = blockIdx.y;           // 0..63
    const int tile = blockIdx.x;           // 0..3
    const int f0   = fg * 4;
    const int th0  = (tile >> 1) * 16;
    const int tw0  = (tile & 1) * 16;
    const int tid  = threadIdx.x;
    const int tx   = tid & 15;
    const int ty   = tid >> 4;

    const bool usex = (f0 < 128);
    const float* rbase = usex ? (rel_x + f0) : (rel_y + (f0 - 128));

    for (int i = tid; i < 484; i += 256) {
        int r = i / 22, c2 = i % 22;
        int hh = th0 - PAD + r;
        int ww = tw0 - PAD + c2;
        bool in = (hh >= 0) & (hh < H) & (ww >= 0) & (ww < W);
        f32x4 k4 = {0.f,0.f,0.f,0.f}, v4 = {0.f,0.f,0.f,0.f};
        if (in) {
            size_t off = ((size_t)(b * HW) + hh * W + ww) * FC + f0;
            s16x4 k16 = *(const s16x4*)&k[off];
            s16x4 v16 = *(const s16x4*)&v[off];
            #pragma unroll
            for (int j = 0; j < 4; ++j) {
                k4[j] = bf2f((ushort)k16[j]);
                v4[j] = bf2f((ushort)v16[j]);
            }
        }
        ksf[i] = k4;
        vsf[i] = v4;
    }
    __syncthreads();

    const int px = (th0 + ty) * W + tw0 + tx;
    s16x4 q4 = *(const s16x4*)&q[((size_t)(b * HW) + px) * FC + f0];
    float q2[4];
    #pragma unroll
    for (int j = 0; j < 4; ++j) q2[j] = bf2f((ushort)q4[j]) * 1.44269504f;

    float sum[4] = {0.f, 0.f, 0.f, 0.f};
    float acc[4] = {0.f, 0.f, 0.f, 0.f};

    const int pbase = ty * 22 + tx;
    #pragma unroll
    for (int dy = 0; dy < KH; ++dy) {
        const int pos0 = pbase + dy * 22;
        f32x4 kr[7], vr[7];
        #pragma unroll
        for (int dx = 0; dx < KW; ++dx) {
            kr[dx] = ksf[pos0 + dx];        // static idx -> registers
            vr[dx] = vsf[pos0 + dx];
        }
        #pragma unroll
        for (int dx = 0; dx < KW; ++dx) {
            const int ridx = usex ? dx : dy;            // uniform
            const float4 rr = *(const float4*)(rbase + ridx * 128);
            const float r4[4] = {rr.x, rr.y, rr.z, rr.w};
            #pragma unroll
            for (int fi = 0; fi < 4; ++fi) {
                float e = __builtin_amdgcn_exp2f(q2[fi] * (kr[dx][fi] + r4[fi]));
                sum[fi] += e;
                acc[fi]  = fmaf(e, vr[dx][fi], acc[fi]);
            }
        }
    }

    #pragma unroll
    for (int fi = 0; fi < 4; ++fi)
        out[((size_t)(b * FC) + f0 + fi) * HW + px] = acc[fi] / sum[fi] + bias[f0 + fi];
}

// ---------------------------------------------------------------------------
extern "C" void kernel_launch(void* const* d_in, const int* in_sizes, int n_in,
                              void* d_out, int out_size, void* d_ws, size_t ws_size,
                              hipStream_t stream)
{
    const float* x     = (const float*)d_in[0];
    const float* Wq    = (const float*)d_in[1];
    const float* Wk    = (const float*)d_in[2];
    const float* Wv    = (const float*)d_in[3];
    const float* rel_x = (const float*)d_in[4];
    const float* rel_y = (const float*)d_in[5];
    const float* bias  = (const float*)d_in[6];
    float* out = (float*)d_out;

    ushort* q  = (ushort*)d_ws;                   // (b,px,f) bf16, 2 MB each
    ushort* kk = q  + (size_t)4 * HW * FC;
    ushort* vv = kk + (size_t)4 * HW * FC;

    qkv_direct_kernel<<<dim3(16, 8, 4), 256, 0, stream>>>(x, Wq, Wk, Wv, q, kk, vv);
    attn_kernel<<<dim3(4, 64, 4), 256, 0, stream>>>(q, kk, vv, rel_x, rel_y, bias, out);
}